// Round 11
// baseline (267.385 us; speedup 1.0000x reference)
//
#include <hip/hip_runtime.h>
#include <math.h>

// Problem constants (fixed by the reference)
#define BB    4
#define TT    1024
#define EE    1024
#define HH    16
#define HDIM  64
#define SS    2048            // T * MULT
#define MROWS 4096            // B * T
// Q scale with log2(e) folded in: softmax runs in exp2 domain.
#define QSCALE 0.18033688011112f   // 0.125 * log2(e)
#define LOG2E  1.4426950408889634f

typedef short  s8v  __attribute__((ext_vector_type(8)));   // 8 bf16 (4 VGPRs)
typedef float  f4v  __attribute__((ext_vector_type(4)));   // 4 fp32 acc

__device__ __forceinline__ unsigned short f2bf(float f) {
    union { float f; unsigned u; } c; c.f = f;
    unsigned u = c.u + 0x7FFFu + ((c.u >> 16) & 1u);   // RNE
    return (unsigned short)(u >> 16);
}
__device__ __forceinline__ float bflo(unsigned u) {
    union { unsigned u; float f; } c; c.u = u << 16; return c.f;
}
__device__ __forceinline__ float bfhi(unsigned u) {
    union { unsigned u; float f; } c; c.u = u & 0xffff0000u; return c.f;
}

// async global->LDS, 16B per lane. LDS dest = wave-uniform base + lane*16.
__device__ __forceinline__ void async16(const void* g, void* l) {
    __builtin_amdgcn_global_load_lds(
        (const __attribute__((address_space(1))) unsigned int*)g,
        (__attribute__((address_space(3))) unsigned int*)l,
        16, 0, 0);
}

// ---------------------------------------------------------------------------
// Fused fp32->bf16 convert: x, Wq, Wk, Wv, Wo, mask in one launch.
// Mask is additionally scaled by log2(e) (softmax runs in exp2 domain).
// ---------------------------------------------------------------------------
__global__ __launch_bounds__(256) void cvt6_kernel(
    const float* __restrict__ x,  const float* __restrict__ wq,
    const float* __restrict__ wk, const float* __restrict__ wv,
    const float* __restrict__ wo, const float* __restrict__ mk,
    unsigned short* __restrict__ xb,  unsigned short* __restrict__ wqb,
    unsigned short* __restrict__ wkb, unsigned short* __restrict__ wvb,
    unsigned short* __restrict__ wob, unsigned short* __restrict__ mbb)
{
    const int total = 3670016;
    int i = blockIdx.x * 256 + threadIdx.x;
    const int stride = gridDim.x * 256;
    for (; i < total; i += stride) {
        const float* s; unsigned short* d; int off; float sc = 1.0f;
        if (i < 1048576)      { s = x;  d = xb;  off = i; }
        else if (i < 1310720) { s = wq; d = wqb; off = i - 1048576; }
        else if (i < 1835008) { s = wk; d = wkb; off = i - 1310720; }
        else if (i < 2359296) { s = wv; d = wvb; off = i - 1835008; }
        else if (i < 2621440) { s = wo; d = wob; off = i - 2359296; }
        else                  { s = mk; d = mbb; off = i - 2621440; sc = LOG2E; }
        float4 v = ((const float4*)s)[off];
        ushort4 o;
        o.x = f2bf(v.x * sc); o.y = f2bf(v.y * sc);
        o.z = f2bf(v.z * sc); o.w = f2bf(v.w * sc);
        ((ushort4*)d)[off] = o;
    }
}

// ---------------------------------------------------------------------------
// FUSED Q+K+V projection (one launch, grid (32,40)):
//   y in [0,8)   : Q = x @ Wq^T  -> qp plain bf16, scaled by QSCALE
//   y in [8,24)  : K = x @ Wk^T  -> kp head layout [B,H,S,HD]
//   y in [24,40) : V = Wv @ x^T  -> vt V^T head layout [B,H,HD,S]
// All three are C = A_panel(128xK) @ W_panel(128xK)^T with the proven m97
// K-loop (128x128 tile, BK=32, global_load_lds w=16, 2 barriers/iter).
// Fusion removes a launch gap and overlaps the two kernels' residency tails
// (1280 blocks = 5/CU queue at the 3/CU residency cap).
// ---------------------------------------------------------------------------
__global__ __launch_bounds__(256, 3) void gemm_qkv_kernel(
    const unsigned short* __restrict__ X,  const unsigned short* __restrict__ Wq,
    const unsigned short* __restrict__ Wk, const unsigned short* __restrict__ Wv,
    const float* __restrict__ bq, const float* __restrict__ bk,
    const float* __restrict__ bv, unsigned short* __restrict__ qp,
    unsigned short* __restrict__ kp, unsigned short* __restrict__ vt)
{
    __shared__ __align__(16) unsigned short As[128 * 32];
    __shared__ __align__(16) unsigned short Bs[128 * 32];

    const int tid = threadIdx.x;
    const int lane = tid & 63, w = tid >> 6;
    const int wm = (w & 1) * 64, wn = (w >> 1) * 64;
    const int col16 = lane & 15, quad = lane >> 4;
    const int y = blockIdx.y;
    const int part = (y < 8) ? 0 : (y < 24) ? 1 : 2;   // 0=Q 1=K 2=V

    // panel row bases: am0 = A rows, wn0 = W rows (both 128-row panels, K=1024)
    int am0, wn0;
    const unsigned short *Apan, *Wpan;
    if (part == 0) {        // Q: A = x tokens, W = Wq rows
        am0 = blockIdx.x * 128; wn0 = y * 128;
        Apan = X + (size_t)am0 * EE;  Wpan = Wq + (size_t)wn0 * EE;
    } else if (part == 1) { // K: A = x tokens, W = Wk rows
        am0 = blockIdx.x * 128; wn0 = (y - 8) * 128;
        Apan = X + (size_t)am0 * EE;  Wpan = Wk + (size_t)wn0 * EE;
    } else {                // V: A = Wv feature rows, W = x tokens
        am0 = (y - 24) * 128; wn0 = blockIdx.x * 128;
        Apan = Wv + (size_t)am0 * EE; Wpan = X + (size_t)wn0 * EE;
    }

    f4v acc[4][4];
#pragma unroll
    for (int i = 0; i < 4; ++i)
#pragma unroll
        for (int j = 0; j < 4; ++j) acc[i][j] = (f4v)0.0f;

    for (int k0 = 0; k0 < EE; k0 += 32) {
#pragma unroll
        for (int it = 0; it < 2; ++it) {
            int f = (it * 4 + w) * 64 + lane;
            int r = f >> 2, g = (f & 3) * 8;
            async16(Apan + (size_t)r * EE + k0 + g, As + (it * 4 + w) * 512);
            async16(Wpan + (size_t)r * EE + k0 + g, Bs + (it * 4 + w) * 512);
        }
        __syncthreads();
        s8v af[4], bf[4];
#pragma unroll
        for (int i = 0; i < 4; ++i)
            af[i] = *(const s8v*)(As + (wm + i * 16 + col16) * 32 + quad * 8);
#pragma unroll
        for (int j = 0; j < 4; ++j)
            bf[j] = *(const s8v*)(Bs + (wn + j * 16 + col16) * 32 + quad * 8);
#pragma unroll
        for (int i = 0; i < 4; ++i)
#pragma unroll
            for (int j = 0; j < 4; ++j)
                acc[i][j] = __builtin_amdgcn_mfma_f32_16x16x32_bf16(
                    af[i], bf[j], acc[i][j], 0, 0, 0);
        __syncthreads();
    }

#pragma unroll
    for (int j = 0; j < 4; ++j) {
        const int n = wn0 + wn + j * 16 + col16;           // W-row index
        const float bn = (part == 0) ? bq[n] : (part == 1) ? bk[n] : 0.0f;
#pragma unroll
        for (int i = 0; i < 4; ++i) {
            const int mb = am0 + wm + i * 16 + quad * 4;
#pragma unroll
            for (int r = 0; r < 4; ++r) {
                const int m = mb + r;                      // A-row index
                if (part == 0) {
                    // Q: m = token, n = feature; scaled bf16, plain layout
                    float c = acc[i][j][r] + bn;
                    qp[(size_t)m * EE + n] = f2bf(c * QSCALE);
                } else if (part == 1) {
                    // K: m = token, n = feature (0..2047) -> [B,H,S,HD]
                    float c = acc[i][j][r] + bn;
                    const int mm = n >> 10, h = (n >> 6) & 15, d = n & 63;
                    const int b_ = m >> 10, t = m & 1023;
                    const int s = 2 * t + mm;
                    kp[((size_t)(b_ * HH + h) * SS + s) * HDIM + d] = f2bf(c);
                } else {
                    // V: m = feature (bias by m), n = token -> V^T [B,H,HD,S]
                    float c = acc[i][j][r] + bv[m];
                    const int mm = m >> 10, h = (m >> 6) & 15, d = m & 63;
                    const int b_ = n >> 10, t = n & 1023;
                    const int s = 2 * t + mm;
                    vt[((size_t)(b_ * HH + h) * HDIM + d) * SS + s] = f2bf(c);
                }
            }
        }
    }
}

// ---------------------------------------------------------------------------
// Output-projection GEMM C = A @ W^T + bias -> fp32, rectangular BM x BN.
// 4 waves arranged 2(m) x 2(n); wave tile (BM/2) x (BN/2).
// ---------------------------------------------------------------------------
template <int Ksz, int Nsz, int BM, int BN>
__global__ __launch_bounds__(256, 4) void gemm_out_kernel(
    const unsigned short* __restrict__ A, const unsigned short* __restrict__ W,
    const float* __restrict__ bias, float* __restrict__ Cout)
{
    constexpr int WM = BM / 2, WN = BN / 2;
    constexpr int MI = WM / 16, NJ = WN / 16;
    __shared__ __align__(16) unsigned short As[BM * 32];
    __shared__ __align__(16) unsigned short Bs[BN * 32];

    const int tid = threadIdx.x;
    const int lane = tid & 63, w = tid >> 6;
    const int wm = (w & 1) * WM, wn = (w >> 1) * WN;
    const int col16 = lane & 15, quad = lane >> 4;
    const int m0 = blockIdx.x * BM;
    const int n0 = blockIdx.y * BN;

    f4v acc[MI][NJ];
#pragma unroll
    for (int i = 0; i < MI; ++i)
#pragma unroll
        for (int j = 0; j < NJ; ++j) acc[i][j] = (f4v)0.0f;

    for (int k0 = 0; k0 < Ksz; k0 += 32) {
#pragma unroll
        for (int it = 0; it < BM / 64; ++it) {
            int f = (it * 4 + w) * 64 + lane;
            int r = f >> 2, g = (f & 3) * 8;
            async16(A + (size_t)(m0 + r) * Ksz + k0 + g, As + (it * 4 + w) * 512);
        }
#pragma unroll
        for (int it = 0; it < BN / 64; ++it) {
            int f = (it * 4 + w) * 64 + lane;
            int r = f >> 2, g = (f & 3) * 8;
            async16(W + (size_t)(n0 + r) * Ksz + k0 + g, Bs + (it * 4 + w) * 512);
        }
        __syncthreads();
        s8v af[MI], bf[NJ];
#pragma unroll
        for (int i = 0; i < MI; ++i)
            af[i] = *(const s8v*)(As + (wm + i * 16 + col16) * 32 + quad * 8);
#pragma unroll
        for (int j = 0; j < NJ; ++j)
            bf[j] = *(const s8v*)(Bs + (wn + j * 16 + col16) * 32 + quad * 8);
#pragma unroll
        for (int i = 0; i < MI; ++i)
#pragma unroll
            for (int j = 0; j < NJ; ++j)
                acc[i][j] = __builtin_amdgcn_mfma_f32_16x16x32_bf16(
                    af[i], bf[j], acc[i][j], 0, 0, 0);
        __syncthreads();
    }

#pragma unroll
    for (int j = 0; j < NJ; ++j) {
        const int n = n0 + wn + j * 16 + col16;
        const float bn = bias[n];
#pragma unroll
        for (int i = 0; i < MI; ++i) {
            const int mb = m0 + wm + i * 16 + quad * 4;
#pragma unroll
            for (int r = 0; r < 4; ++r) {
                const int m = mb + r;
                Cout[(size_t)m * Nsz + n] = acc[i][j][r] + bn;
            }
        }
    }
}

// ---------------------------------------------------------------------------
// Flash attention v5 (FROZEN -- proven 76-77 us, best of 9 variants):
// K reg-staged into LDS one iter ahead (T14), V reg-staged likewise
// (split: K+mask before barrier B, V after pk pack), P in K-buffers after
// barrier C, wave-private rows (no barrier D). 3 barriers/iter.
// 4 blocks/CU, 16 waves/CU. All-global and reuse variants (v6-v9) regressed:
// LDS-pipe vs TLP trade is balanced here.
// ---------------------------------------------------------------------------
__global__ __launch_bounds__(256, 4) void attn_mfma5_kernel(
    const unsigned short* __restrict__ Q, const unsigned short* __restrict__ Kh,
    const unsigned short* __restrict__ Vt, const unsigned short* __restrict__ Mb,
    unsigned short* __restrict__ O)
{
    constexpr int PT = 68;   // 136B pitch: conflict-free b128/b64 patterns
    __shared__ __align__(16) unsigned short K0[64 * PT];  // K half0, then P0
    __shared__ __align__(16) unsigned short K1[64 * PT];  // K half1, then P1
    __shared__ __align__(16) unsigned short V0[64 * PT];  // V^T half0 [d][s]
    __shared__ __align__(16) unsigned short V1[64 * PT];  // V^T half1 [d][s]

    const int tid = threadIdx.x;
    const int lane = tid & 63, w = tid >> 6;
    const int col16 = lane & 15, quad = lane >> 4;

    // XCD swizzle: v = gid&7 (virtual XCD), bh = v*8 + (j>>4), t0 = (j&15)*64
    const int gid = blockIdx.x;
    const int v = gid & 7, j = gid >> 3;
    const int bh = v * 8 + (j >> 4);
    const int t0 = (j & 15) * 64;
    const int b_ = bh >> 4, h = bh & 15;

    // Q fragments in registers: this lane's t-row = w*16+col16, k-slices
    const unsigned short* Qrow =
        Q + (size_t)(b_ * TT + t0 + w * 16 + col16) * EE + h * HDIM;
    const s8v qf0 = *(const s8v*)(Qrow + quad * 8);
    const s8v qf1 = *(const s8v*)(Qrow + 32 + quad * 8);

    f4v oacc[4];
#pragma unroll
    for (int jd = 0; jd < 4; ++jd) oacc[jd] = (f4v)0.0f;
    float mrun = -INFINITY;
    f4v l4 = (f4v)0.0f;           // per-lane partial row-sum (4 s-slots)

    const unsigned short* Kb   = Kh + (size_t)bh * SS * HDIM;
    const unsigned short* Vb   = Vt + (size_t)bh * HDIM * SS;
    const unsigned short* Mrow = Mb + (size_t)b_ * TT * TT
                               + (size_t)(t0 + w * 16 + col16) * TT;
    const int myrow = (w * 16 + col16) * PT;   // this lane's t-row in LDS
    const int r0 = tid >> 3, c0 = (tid & 7) * 8;   // staging row/col

    // T14 staged tile: NAMED registers only (arrays risk scratch demotion)
    uint4 kA0, kA1, kB0, kB1;   // K half0/half1, rows r0 and r0+32
    uint4 vA0, vA1, vB0, vB1;   // V^T half0/half1
    uint2 mA0, mA1, mA2, mA3;   // mask cols for this lane's t-row

#define PREF_K(T2B)                                                            \
    kA0 = *(const uint4*)(Kb + (size_t)((T2B) + r0) * HDIM + c0);              \
    kA1 = *(const uint4*)(Kb + (size_t)((T2B) + r0 + 32) * HDIM + c0);         \
    kB0 = *(const uint4*)(Kb + (size_t)(1024 + (T2B) + r0) * HDIM + c0);       \
    kB1 = *(const uint4*)(Kb + (size_t)(1024 + (T2B) + r0 + 32) * HDIM + c0);
#define PREF_V(T2B)                                                            \
    vA0 = *(const uint4*)(Vb + (size_t)r0 * SS + (T2B) + c0);                  \
    vA1 = *(const uint4*)(Vb + (size_t)(r0 + 32) * SS + (T2B) + c0);           \
    vB0 = *(const uint4*)(Vb + (size_t)r0 * SS + 1024 + (T2B) + c0);           \
    vB1 = *(const uint4*)(Vb + (size_t)(r0 + 32) * SS + 1024 + (T2B) + c0);
#define PREF_M(T2B)                                                            \
    mA0 = *(const uint2*)(Mrow + (T2B) + 0 * 16 + quad * 4);                   \
    mA1 = *(const uint2*)(Mrow + (T2B) + 1 * 16 + quad * 4);                   \
    mA2 = *(const uint2*)(Mrow + (T2B) + 2 * 16 + quad * 4);                   \
    mA3 = *(const uint2*)(Mrow + (T2B) + 3 * 16 + quad * 4);

    // prologue: tile 0 fully staged
    PREF_K(0)
    PREF_V(0)
    PREF_M(0)

    for (int it16 = 0; it16 < 16; ++it16) {
        __syncthreads();  // (A) prev iteration's PV reads done

        // write staged tile (regs -> LDS); loads long since completed
        *(uint4*)(K0 + r0 * PT + c0)        = kA0;
        *(uint4*)(K0 + (r0 + 32) * PT + c0) = kA1;
        *(uint4*)(K1 + r0 * PT + c0)        = kB0;
        *(uint4*)(K1 + (r0 + 32) * PT + c0) = kB1;
        *(uint4*)(V0 + r0 * PT + c0)        = vA0;
        *(uint4*)(V0 + (r0 + 32) * PT + c0) = vA1;
        *(uint4*)(V1 + r0 * PT + c0)        = vB0;
        *(uint4*)(V1 + (r0 + 32) * PT + c0) = vB1;

        // S-acc init from current mask regs (register-only; pre-B is fine)
        f4v s0acc[4], s1acc[4];
        {
            f4v mv;
            mv[0] = bflo(mA0.x); mv[1] = bfhi(mA0.x);
            mv[2] = bflo(mA0.y); mv[3] = bfhi(mA0.y);
            s0acc[0] = mv; s1acc[0] = mv;
            mv[0] = bflo(mA1.x); mv[1] = bfhi(mA1.x);
            mv[2] = bflo(mA1.y); mv[3] = bfhi(mA1.y);
            s0acc[1] = mv; s1acc[1] = mv;
            mv[0] = bflo(mA2.x); mv[1] = bfhi(mA2.x);
            mv[2] = bflo(mA2.y); mv[3] = bfhi(mA2.y);
            s0acc[2] = mv; s1acc[2] = mv;
            mv[0] = bflo(mA3.x); mv[1] = bfhi(mA3.x);
            mv[2] = bflo(mA3.y); mv[3] = bfhi(mA3.y);
            s0acc[3] = mv; s1acc[3] = mv;
        }

        // T14a: K(next)+mask(next) in flight across the whole compute phase
        const int t2n = ((it16 + 1) & 15) * 64;
        PREF_K(t2n)
        PREF_M(t2n)

        __syncthreads();  // (B) staged tile visible to all waves

        // S^T halves: A=K (m=s), B=Q (n=t); mask pre-loaded in C-operand
        __builtin_amdgcn_s_setprio(1);
#pragma unroll
        for (int ks = 0; ks < 2; ++ks) {
            const s8v bq_ = ks ? qf1 : qf0;
#pragma unroll
            for (int js = 0; js < 4; ++js) {
                s8v ak0 = *(const s8v*)(K0 + (js * 16 + col16) * PT + ks * 32 + quad * 8);
                s8v ak1 = *(const s8v*)(K1 + (js * 16 + col16) * PT + ks * 32 + quad * 8);
                s0acc[js] = __builtin_amdgcn_mfma_f32_16x16x32_bf16(ak0, bq_, s0acc[js], 0, 0, 0);
                s1acc[js] = __builtin_amdgcn_mfma_f32_16x16x32_bf16(ak1, bq_, s1acc[js], 0, 0, 0);
            }
        }
        __builtin_amdgcn_s_setprio(0);

        // per-lane max over this lane's 32 S values
        float tm0 = fmaxf(fmaxf(s0acc[0][0], s0acc[0][1]), fmaxf(s0acc[0][2], s0acc[0][3]));
        float tm1 = fmaxf(fmaxf(s0acc[1][0], s0acc[1][1]), fmaxf(s0acc[1][2], s0acc[1][3]));
        float tm2 = fmaxf(fmaxf(s0acc[2][0], s0acc[2][1]), fmaxf(s0acc[2][2], s0acc[2][3]));
        float tm3 = fmaxf(fmaxf(s0acc[3][0], s0acc[3][1]), fmaxf(s0acc[3][2], s0acc[3][3]));
        float tn0 = fmaxf(fmaxf(s1acc[0][0], s1acc[0][1]), fmaxf(s1acc[0][2], s1acc[0][3]));
        float tn1 = fmaxf(fmaxf(s1acc[1][0], s1acc[1][1]), fmaxf(s1acc[1][2], s1acc[1][3]));
        float tn2 = fmaxf(fmaxf(s1acc[2][0], s1acc[2][1]), fmaxf(s1acc[2][2], s1acc[2][3]));
        float tn3 = fmaxf(fmaxf(s1acc[3][0], s1acc[3][1]), fmaxf(s1acc[3][2], s1acc[3][3]));
        float tmax = fmaxf(fmaxf(fmaxf(tm0, tm1), fmaxf(tm2, tm3)),
                           fmaxf(fmaxf(tn0, tn1), fmaxf(tn2, tn3)));

        // defer-max: rescale only if some lane's max grew past mrun + 10
        if (!__all(tmax - mrun <= 10.0f)) {
            float tfull = fmaxf(tmax, __shfl_xor(tmax, 16));
            tfull = fmaxf(tfull, __shfl_xor(tfull, 32));
            const float mnew = fmaxf(mrun, tfull);
            const float scl = __builtin_amdgcn_exp2f(mrun - mnew);  // 0 on 1st
            l4 *= scl;
            float sclr[4];
#pragma unroll
            for (int r = 0; r < 4; ++r) sclr[r] = __shfl(scl, quad * 4 + r);
#pragma unroll
            for (int jd = 0; jd < 4; ++jd)
#pragma unroll
                for (int r = 0; r < 4; ++r) oacc[jd][r] *= sclr[r];
            mrun = mnew;
        }

        // exp2 + pack to bf16 (pre-barrier-C; only stores go after C)
        unsigned pk0[8], pk1[8];
#pragma unroll
        for (int js = 0; js < 4; ++js) {
            f4v p0 = s0acc[js] - mrun;
            f4v p1 = s1acc[js] - mrun;
#pragma unroll
            for (int r = 0; r < 4; ++r) {
                p0[r] = __builtin_amdgcn_exp2f(p0[r]);
                p1[r] = __builtin_amdgcn_exp2f(p1[r]);
            }
            l4 += p0 + p1;
            __asm__("v_cvt_pk_bf16_f32 %0, %1, %2" : "=v"(pk0[js*2])   : "v"(p0[0]), "v"(p0[1]));
            __asm__("v_cvt_pk_bf16_f32 %0, %1, %2" : "=v"(pk0[js*2+1]) : "v"(p0[2]), "v"(p0[3]));
            __asm__("v_cvt_pk_bf16_f32 %0, %1, %2" : "=v"(pk1[js*2])   : "v"(p1[0]), "v"(p1[1]));
            __asm__("v_cvt_pk_bf16_f32 %0, %1, %2" : "=v"(pk1[js*2+1]) : "v"(p1[2]), "v"(p1[3]));
        }

        // T14b: V(next) in flight across P-store + PV (s-acc now dead)
        PREF_V(t2n)

        __syncthreads();  // (C) all waves done reading K0/K1

        // P store (wave-private rows) -> no barrier before readback:
        // same-wave same-address LDS ordering via lgkmcnt (compiler-inserted)
#pragma unroll
        for (int js = 0; js < 4; ++js) {
            *(uint2*)(K0 + myrow + js * 16 + quad * 4) = make_uint2(pk0[js*2], pk0[js*2+1]);
            *(uint2*)(K1 + myrow + js * 16 + quad * 4) = make_uint2(pk1[js*2], pk1[js*2+1]);
        }

        // O += P0.V0 + P1.V1 : A[m=t][k=s] from K0/K1, B[n=d][k=s] from V0/V1
        __builtin_amdgcn_s_setprio(1);
#pragma unroll
        for (int ks = 0; ks < 2; ++ks) {
            s8v p0 = *(const s8v*)(K0 + myrow + ks * 32 + quad * 8);
            s8v p1 = *(const s8v*)(K1 + myrow + ks * 32 + quad * 8);
#pragma unroll
            for (int jd = 0; jd < 4; ++jd) {
                s8v v0_ = *(const s8v*)(V0 + (jd * 16 + col16) * PT + ks * 32 + quad * 8);
                s8v v1_ = *(const s8v*)(V1 + (jd * 16 + col16) * PT + ks * 32 + quad * 8);
                oacc[jd] = __builtin_amdgcn_mfma_f32_16x16x32_bf16(p0, v0_, oacc[jd], 0, 0, 0);
                oacc[jd] = __builtin_amdgcn_mfma_f32_16x16x32_bf16(p1, v1_, oacc[jd], 0, 0, 0);
            }
        }
        __builtin_amdgcn_s_setprio(0);
    }
#undef PREF_K
#undef PREF_V
#undef PREF_M

    // epilogue: reduce row-sum partials (4 s-slots, then cross-quad),
    // normalize and write bf16
    float lr = l4[0] + l4[1] + l4[2] + l4[3];
    lr += __shfl_xor(lr, 16);
    lr += __shfl_xor(lr, 32);
    const float inv = 1.0f / lr;
    float invr[4];
#pragma unroll
    for (int r = 0; r < 4; ++r) invr[r] = __shfl(inv, quad * 4 + r);
#pragma unroll
    for (int r = 0; r < 4; ++r) {
        const int t = t0 + w * 16 + quad * 4 + r;
#pragma unroll
        for (int jd = 0; jd < 4; ++jd)
            O[(size_t)(b_ * TT + t) * EE + h * HDIM + jd * 16 + col16] =
                f2bf(oacc[jd][r] * invr[r]);
    }
}

// ---------------------------------------------------------------------------
extern "C" void kernel_launch(void* const* d_in, const int* in_sizes, int n_in,
                              void* d_out, int out_size, void* d_ws, size_t ws_size,
                              hipStream_t stream)
{
    (void)in_sizes; (void)n_in; (void)out_size; (void)ws_size;

    const float* x    = (const float*)d_in[0];
    const float* mask = (const float*)d_in[1];
    const float* Wq   = (const float*)d_in[2];
    const float* bq   = (const float*)d_in[3];
    const float* Wk   = (const float*)d_in[4];
    const float* bk   = (const float*)d_in[5];
    const float* Wv   = (const float*)d_in[6];
    const float* bv   = (const float*)d_in[7];
    const float* Wo   = (const float*)d_in[8];
    const float* bo   = (const float*)d_in[9];
    float* out = (float*)d_out;

    // workspace carve (ushort units): 42M ushorts = 84 MB
    unsigned short* xb  = (unsigned short*)d_ws;
    unsigned short* wqb = xb  + (size_t)MROWS * EE;          // 4M
    unsigned short* wkb = wqb + (size_t)EE * EE;             // 1M
    unsigned short* wvb = wkb + (size_t)2 * EE * EE;         // 2M
    unsigned short* wob = wvb + (size_t)2 * EE * EE;         // 2M
    unsigned short* mb  = wob + (size_t)EE * EE;             // 1M
    unsigned short* qp  = mb  + (size_t)BB * TT * TT;        // 4M
    unsigned short* kp  = qp  + (size_t)MROWS * EE;          // 4M (head layout)
    unsigned short* vt  = kp  + (size_t)BB * HH * SS * HDIM; // 8M ([B,H,HD,S])
    unsigned short* ao  = vt  + (size_t)BB * HH * SS * HDIM; // 8M

    dim3 blk(256);

    // fused fp32->bf16 conversion (x + 4 weights + mask; mask *= log2e)
    cvt6_kernel<<<4096, blk, 0, stream>>>(x, Wq, Wk, Wv, Wo, mask,
                                          xb, wqb, wkb, wvb, wob, mb);
    // FUSED Q+K+V projection: grid (32,40) = 1280 blocks (5/CU queue depth)
    gemm_qkv_kernel<<<dim3(32, 40), blk, 0, stream>>>(
        xb, wqb, wkb, wvb, bq, bk, bv, qp, kp, vt);
    // attention (v5 frozen: 76-77 us proven)
    attn_mfma5_kernel<<<dim3(1024), blk, 0, stream>>>(qp, kp, vt, mb, ao);
    // output projection -> fp32 out (128x64 tile: 512 blocks, 2/CU)
    gemm_out_kernel<EE, EE, 128, 64><<<dim3(32, 16), blk, 0, stream>>>(
        ao, wob, bo, out);
}

// Round 13
// 266.755 us; speedup vs baseline: 1.0024x; 1.0024x over previous
//
#include <hip/hip_runtime.h>
#include <math.h>

// Problem constants (fixed by the reference)
#define BB    4
#define TT    1024
#define EE    1024
#define HH    16
#define HDIM  64
#define SS    2048            // T * MULT
#define MROWS 4096            // B * T
// Q scale with log2(e) folded in: softmax runs in exp2 domain.
#define QSCALE 0.18033688011112f   // 0.125 * log2(e)
#define LOG2E  1.4426950408889634f

typedef short  s8v  __attribute__((ext_vector_type(8)));   // 8 bf16 (4 VGPRs)
typedef float  f4v  __attribute__((ext_vector_type(4)));   // 4 fp32 acc

__device__ __forceinline__ unsigned short f2bf(float f) {
    union { float f; unsigned u; } c; c.f = f;
    unsigned u = c.u + 0x7FFFu + ((c.u >> 16) & 1u);   // RNE
    return (unsigned short)(u >> 16);
}
__device__ __forceinline__ float bflo(unsigned u) {
    union { unsigned u; float f; } c; c.u = u << 16; return c.f;
}
__device__ __forceinline__ float bfhi(unsigned u) {
    union { unsigned u; float f; } c; c.u = u & 0xffff0000u; return c.f;
}

// async global->LDS, 16B per lane. LDS dest = wave-uniform base + lane*16.
__device__ __forceinline__ void async16(const void* g, void* l) {
    __builtin_amdgcn_global_load_lds(
        (const __attribute__((address_space(1))) unsigned int*)g,
        (__attribute__((address_space(3))) unsigned int*)l,
        16, 0, 0);
}

// ---------------------------------------------------------------------------
// Fused fp32->bf16 convert: x, Wq, Wk, Wv, Wo, mask in one launch.
// Mask is additionally scaled by log2(e) (softmax runs in exp2 domain).
// ---------------------------------------------------------------------------
__global__ __launch_bounds__(256) void cvt6_kernel(
    const float* __restrict__ x,  const float* __restrict__ wq,
    const float* __restrict__ wk, const float* __restrict__ wv,
    const float* __restrict__ wo, const float* __restrict__ mk,
    unsigned short* __restrict__ xb,  unsigned short* __restrict__ wqb,
    unsigned short* __restrict__ wkb, unsigned short* __restrict__ wvb,
    unsigned short* __restrict__ wob, unsigned short* __restrict__ mbb)
{
    const int total = 3670016;
    int i = blockIdx.x * 256 + threadIdx.x;
    const int stride = gridDim.x * 256;
    for (; i < total; i += stride) {
        const float* s; unsigned short* d; int off; float sc = 1.0f;
        if (i < 1048576)      { s = x;  d = xb;  off = i; }
        else if (i < 1310720) { s = wq; d = wqb; off = i - 1048576; }
        else if (i < 1835008) { s = wk; d = wkb; off = i - 1310720; }
        else if (i < 2359296) { s = wv; d = wvb; off = i - 1835008; }
        else if (i < 2621440) { s = wo; d = wob; off = i - 2359296; }
        else                  { s = mk; d = mbb; off = i - 2621440; sc = LOG2E; }
        float4 v = ((const float4*)s)[off];
        ushort4 o;
        o.x = f2bf(v.x * sc); o.y = f2bf(v.y * sc);
        o.z = f2bf(v.z * sc); o.w = f2bf(v.w * sc);
        ((ushort4*)d)[off] = o;
    }
}

// ---------------------------------------------------------------------------
// FUSED Q+K+V projection (one launch, grid (32,40)):
//   y in [0,8)   : Q = x @ Wq^T  -> qp plain bf16 [token][1024], QSCALE'd
//   y in [8,24)  : K = x @ Wk^T  -> kp plain bf16 [token][2048]
//   y in [24,40) : V = Wv @ x^T  -> vt plain bf16 V^T [feature 2048][4096]
// ALL epilogues are plain contiguous C[m][n] stores (v11's scattered K/V
// head-layout stores caused 33 MB write-RMW amplification + ~8 VALU/elem
// index math; attention now consumes plain layouts directly via
// (mm,t)-ordered halves). Proven m97 K-loop untouched.
// ---------------------------------------------------------------------------
__global__ __launch_bounds__(256, 4) void gemm_qkv_kernel(
    const unsigned short* __restrict__ X,  const unsigned short* __restrict__ Wq,
    const unsigned short* __restrict__ Wk, const unsigned short* __restrict__ Wv,
    const float* __restrict__ bq, const float* __restrict__ bk,
    const float* __restrict__ bv, unsigned short* __restrict__ qp,
    unsigned short* __restrict__ kp, unsigned short* __restrict__ vt)
{
    __shared__ __align__(16) unsigned short As[128 * 32];
    __shared__ __align__(16) unsigned short Bs[128 * 32];

    const int tid = threadIdx.x;
    const int lane = tid & 63, w = tid >> 6;
    const int wm = (w & 1) * 64, wn = (w >> 1) * 64;
    const int col16 = lane & 15, quad = lane >> 4;
    const int y = blockIdx.y;
    const int part = (y < 8) ? 0 : (y < 24) ? 1 : 2;   // 0=Q 1=K 2=V

    // panel row bases: am0 = A rows, wn0 = W rows (both 128-row panels, K=1024)
    int am0, wn0;
    const unsigned short *Apan, *Wpan;
    if (part == 0) {        // Q: A = x tokens, W = Wq rows
        am0 = blockIdx.x * 128; wn0 = y * 128;
        Apan = X + (size_t)am0 * EE;  Wpan = Wq + (size_t)wn0 * EE;
    } else if (part == 1) { // K: A = x tokens, W = Wk rows
        am0 = blockIdx.x * 128; wn0 = (y - 8) * 128;
        Apan = X + (size_t)am0 * EE;  Wpan = Wk + (size_t)wn0 * EE;
    } else {                // V: A = Wv feature rows, W = x tokens
        am0 = (y - 24) * 128; wn0 = blockIdx.x * 128;
        Apan = Wv + (size_t)am0 * EE; Wpan = X + (size_t)wn0 * EE;
    }

    f4v acc[4][4];
#pragma unroll
    for (int i = 0; i < 4; ++i)
#pragma unroll
        for (int j = 0; j < 4; ++j) acc[i][j] = (f4v)0.0f;

    for (int k0 = 0; k0 < EE; k0 += 32) {
#pragma unroll
        for (int it = 0; it < 2; ++it) {
            int f = (it * 4 + w) * 64 + lane;
            int r = f >> 2, g = (f & 3) * 8;
            async16(Apan + (size_t)r * EE + k0 + g, As + (it * 4 + w) * 512);
            async16(Wpan + (size_t)r * EE + k0 + g, Bs + (it * 4 + w) * 512);
        }
        __syncthreads();
        s8v af[4], bf[4];
#pragma unroll
        for (int i = 0; i < 4; ++i)
            af[i] = *(const s8v*)(As + (wm + i * 16 + col16) * 32 + quad * 8);
#pragma unroll
        for (int j = 0; j < 4; ++j)
            bf[j] = *(const s8v*)(Bs + (wn + j * 16 + col16) * 32 + quad * 8);
#pragma unroll
        for (int i = 0; i < 4; ++i)
#pragma unroll
            for (int j = 0; j < 4; ++j)
                acc[i][j] = __builtin_amdgcn_mfma_f32_16x16x32_bf16(
                    af[i], bf[j], acc[i][j], 0, 0, 0);
        __syncthreads();
    }

    // plain contiguous epilogues (coalesced 32B chunks, full line coverage)
#pragma unroll
    for (int j = 0; j < 4; ++j) {
        const int n = wn0 + wn + j * 16 + col16;
        const float bn = (part == 0) ? bq[n] : (part == 1) ? bk[n] : 0.0f;
#pragma unroll
        for (int i = 0; i < 4; ++i) {
            const int mb = am0 + wm + i * 16 + quad * 4;
#pragma unroll
            for (int r = 0; r < 4; ++r) {
                const int m = mb + r;
                if (part == 0) {
                    qp[(size_t)m * EE + n] = f2bf((acc[i][j][r] + bn) * QSCALE);
                } else if (part == 1) {
                    kp[(size_t)m * 2048 + n] = f2bf(acc[i][j][r] + bn);
                } else {
                    vt[(size_t)m * 4096 + n] = f2bf(acc[i][j][r] + bv[m]);
                }
            }
        }
    }
}

// ---------------------------------------------------------------------------
// Output-projection GEMM C = A @ W^T + bias -> fp32, rectangular BM x BN.
// ---------------------------------------------------------------------------
template <int Ksz, int Nsz, int BM, int BN>
__global__ __launch_bounds__(256, 4) void gemm_out_kernel(
    const unsigned short* __restrict__ A, const unsigned short* __restrict__ W,
    const float* __restrict__ bias, float* __restrict__ Cout)
{
    constexpr int WM = BM / 2, WN = BN / 2;
    constexpr int MI = WM / 16, NJ = WN / 16;
    __shared__ __align__(16) unsigned short As[BM * 32];
    __shared__ __align__(16) unsigned short Bs[BN * 32];

    const int tid = threadIdx.x;
    const int lane = tid & 63, w = tid >> 6;
    const int wm = (w & 1) * WM, wn = (w >> 1) * WN;
    const int col16 = lane & 15, quad = lane >> 4;
    const int m0 = blockIdx.x * BM;
    const int n0 = blockIdx.y * BN;

    f4v acc[MI][NJ];
#pragma unroll
    for (int i = 0; i < MI; ++i)
#pragma unroll
        for (int j = 0; j < NJ; ++j) acc[i][j] = (f4v)0.0f;

    for (int k0 = 0; k0 < Ksz; k0 += 32) {
#pragma unroll
        for (int it = 0; it < BM / 64; ++it) {
            int f = (it * 4 + w) * 64 + lane;
            int r = f >> 2, g = (f & 3) * 8;
            async16(A + (size_t)(m0 + r) * Ksz + k0 + g, As + (it * 4 + w) * 512);
        }
#pragma unroll
        for (int it = 0; it < BN / 64; ++it) {
            int f = (it * 4 + w) * 64 + lane;
            int r = f >> 2, g = (f & 3) * 8;
            async16(W + (size_t)(n0 + r) * Ksz + k0 + g, Bs + (it * 4 + w) * 512);
        }
        __syncthreads();
        s8v af[MI], bf[NJ];
#pragma unroll
        for (int i = 0; i < MI; ++i)
            af[i] = *(const s8v*)(As + (wm + i * 16 + col16) * 32 + quad * 8);
#pragma unroll
        for (int j = 0; j < NJ; ++j)
            bf[j] = *(const s8v*)(Bs + (wn + j * 16 + col16) * 32 + quad * 8);
#pragma unroll
        for (int i = 0; i < MI; ++i)
#pragma unroll
            for (int j = 0; j < NJ; ++j)
                acc[i][j] = __builtin_amdgcn_mfma_f32_16x16x32_bf16(
                    af[i], bf[j], acc[i][j], 0, 0, 0);
        __syncthreads();
    }

#pragma unroll
    for (int j = 0; j < NJ; ++j) {
        const int n = n0 + wn + j * 16 + col16;
        const float bn = bias[n];
#pragma unroll
        for (int i = 0; i < MI; ++i) {
            const int mb = m0 + wm + i * 16 + quad * 4;
#pragma unroll
            for (int r = 0; r < 4; ++r) {
                const int m = mb + r;
                Cout[(size_t)m * Nsz + n] = acc[i][j][r] + bn;
            }
        }
    }
}

// ---------------------------------------------------------------------------
// Flash attention v12: v5 pipeline structure (FROZEN: T14 reg-staged K/V,
// split prefetch, P in K-buffers, 3 barriers/iter, 4 blocks/CU) with
// (mm, t)-ORDERED HALVES consuming plain K/V layouts:
//   half0 = (mm=0, tokens t2b..t2b+63), half1 = (mm=1, same tokens).
// s-order within the softmax sum is free; only K, V and the mask column
// mapping must agree. Reference mask col = s mod 1024 with s = 2t+mm ->
// col = (2t+mm) & 1023. One uint4 per js covers cols (2tk)&1023..+7 =
// both mm for 4 tokens (even ushorts -> mm0, odd -> mm1).
//   K rows: kp + (b*1024+t)*2048 + mm*1024 + h*64   (128 B contiguous)
//   V rows: vt + (mm*1024+h*64+d)*4096 + b*1024 + t (128 B contiguous)
// Staging reads are 8 rows x 128 B per instr, T14-latency-hidden (same
// class as v5's proven V staging).
// ---------------------------------------------------------------------------
__global__ __launch_bounds__(256, 4) void attn_mfma12_kernel(
    const unsigned short* __restrict__ Q, const unsigned short* __restrict__ Kp,
    const unsigned short* __restrict__ Vt, const unsigned short* __restrict__ Mb,
    unsigned short* __restrict__ O)
{
    constexpr int PT = 68;   // 136B pitch: conflict-free b128/b64 patterns
    __shared__ __align__(16) unsigned short K0[64 * PT];  // K mm=0, then P0
    __shared__ __align__(16) unsigned short K1[64 * PT];  // K mm=1, then P1
    __shared__ __align__(16) unsigned short V0[64 * PT];  // V^T mm=0 [d][t]
    __shared__ __align__(16) unsigned short V1[64 * PT];  // V^T mm=1 [d][t]

    const int tid = threadIdx.x;
    const int lane = tid & 63, w = tid >> 6;
    const int col16 = lane & 15, quad = lane >> 4;

    // XCD swizzle: v = gid&7 (virtual XCD), bh = v*8 + (j>>4), t0 = (j&15)*64
    const int gid = blockIdx.x;
    const int v = gid & 7, j = gid >> 3;
    const int bh = v * 8 + (j >> 4);
    const int t0 = (j & 15) * 64;
    const int b_ = bh >> 4, h = bh & 15;

    // Q fragments in registers: this lane's t-row = w*16+col16, k-slices
    const unsigned short* Qrow =
        Q + (size_t)(b_ * TT + t0 + w * 16 + col16) * EE + h * HDIM;
    const s8v qf0 = *(const s8v*)(Qrow + quad * 8);
    const s8v qf1 = *(const s8v*)(Qrow + 32 + quad * 8);

    f4v oacc[4];
#pragma unroll
    for (int jd = 0; jd < 4; ++jd) oacc[jd] = (f4v)0.0f;
    float mrun = -INFINITY;
    f4v l4 = (f4v)0.0f;           // per-lane partial row-sum (4 s-slots)

    // plain-layout bases (mm halves)
    const unsigned short* Kb0 = Kp + (size_t)(b_ * 1024) * 2048 + h * 64;
    const unsigned short* Kb1 = Kb0 + 1024;                       // mm=1
    const unsigned short* Vb0 = Vt + (size_t)(h * 64) * 4096 + b_ * 1024;
    const unsigned short* Vb1 = Vb0 + (size_t)1024 * 4096;        // mm=1
    const unsigned short* Mrow = Mb + (size_t)b_ * TT * TT
                               + (size_t)(t0 + w * 16 + col16) * TT;
    const int myrow = (w * 16 + col16) * PT;   // this lane's t-row in LDS
    const int r0 = tid >> 3, c0 = (tid & 7) * 8;   // staging row/col

    // T14 staged tile: NAMED registers only (arrays risk scratch demotion)
    uint4 kA0, kA1, kB0, kB1;   // K mm0/mm1, rows r0 and r0+32
    uint4 vA0, vA1, vB0, vB1;   // V^T mm0/mm1
    uint4 mA0, mA1, mA2, mA3;   // mask cols (2tk)&1023..+7 per js

#define PREF_K(T2B)                                                            \
    kA0 = *(const uint4*)(Kb0 + (size_t)((T2B) + r0) * 2048 + c0);             \
    kA1 = *(const uint4*)(Kb0 + (size_t)((T2B) + r0 + 32) * 2048 + c0);        \
    kB0 = *(const uint4*)(Kb1 + (size_t)((T2B) + r0) * 2048 + c0);             \
    kB1 = *(const uint4*)(Kb1 + (size_t)((T2B) + r0 + 32) * 2048 + c0);
#define PREF_V(T2B)                                                            \
    vA0 = *(const uint4*)(Vb0 + (size_t)r0 * 4096 + (T2B) + c0);               \
    vA1 = *(const uint4*)(Vb0 + (size_t)(r0 + 32) * 4096 + (T2B) + c0);        \
    vB0 = *(const uint4*)(Vb1 + (size_t)r0 * 4096 + (T2B) + c0);               \
    vB1 = *(const uint4*)(Vb1 + (size_t)(r0 + 32) * 4096 + (T2B) + c0);
#define PREF_M(T2B)                                                            \
    {                                                                          \
        const unsigned short* Mx = Mrow + ((2 * (T2B)) & 1023);                \
        mA0 = *(const uint4*)(Mx + 0 * 32 + quad * 8);                         \
        mA1 = *(const uint4*)(Mx + 1 * 32 + quad * 8);                         \
        mA2 = *(const uint4*)(Mx + 2 * 32 + quad * 8);                         \
        mA3 = *(const uint4*)(Mx + 3 * 32 + quad * 8);                         \
    }

    // prologue: tile 0 fully staged
    PREF_K(0)
    PREF_V(0)
    PREF_M(0)

    for (int it16 = 0; it16 < 16; ++it16) {
        __syncthreads();  // (A) prev iteration's PV reads done

        // write staged tile (regs -> LDS); loads long since completed
        *(uint4*)(K0 + r0 * PT + c0)        = kA0;
        *(uint4*)(K0 + (r0 + 32) * PT + c0) = kA1;
        *(uint4*)(K1 + r0 * PT + c0)        = kB0;
        *(uint4*)(K1 + (r0 + 32) * PT + c0) = kB1;
        *(uint4*)(V0 + r0 * PT + c0)        = vA0;
        *(uint4*)(V0 + (r0 + 32) * PT + c0) = vA1;
        *(uint4*)(V1 + r0 * PT + c0)        = vB0;
        *(uint4*)(V1 + (r0 + 32) * PT + c0) = vB1;

        // S-acc init from mask regs: even ushorts -> mm0, odd -> mm1
        f4v s0acc[4], s1acc[4];
        {
            f4v mv;
            mv[0] = bflo(mA0.x); mv[1] = bflo(mA0.y);
            mv[2] = bflo(mA0.z); mv[3] = bflo(mA0.w); s0acc[0] = mv;
            mv[0] = bfhi(mA0.x); mv[1] = bfhi(mA0.y);
            mv[2] = bfhi(mA0.z); mv[3] = bfhi(mA0.w); s1acc[0] = mv;
            mv[0] = bflo(mA1.x); mv[1] = bflo(mA1.y);
            mv[2] = bflo(mA1.z); mv[3] = bflo(mA1.w); s0acc[1] = mv;
            mv[0] = bfhi(mA1.x); mv[1] = bfhi(mA1.y);
            mv[2] = bfhi(mA1.z); mv[3] = bfhi(mA1.w); s1acc[1] = mv;
            mv[0] = bflo(mA2.x); mv[1] = bflo(mA2.y);
            mv[2] = bflo(mA2.z); mv[3] = bflo(mA2.w); s0acc[2] = mv;
            mv[0] = bfhi(mA2.x); mv[1] = bfhi(mA2.y);
            mv[2] = bfhi(mA2.z); mv[3] = bfhi(mA2.w); s1acc[2] = mv;
            mv[0] = bflo(mA3.x); mv[1] = bflo(mA3.y);
            mv[2] = bflo(mA3.z); mv[3] = bflo(mA3.w); s0acc[3] = mv;
            mv[0] = bfhi(mA3.x); mv[1] = bfhi(mA3.y);
            mv[2] = bfhi(mA3.z); mv[3] = bfhi(mA3.w); s1acc[3] = mv;
        }

        // T14a: K(next)+mask(next) in flight across the whole compute phase
        const int t2n = ((it16 + 1) & 15) * 64;
        PREF_K(t2n)
        PREF_M(t2n)

        __syncthreads();  // (B) staged tile visible to all waves

        // S^T halves: A=K (m=token-row), B=Q (n=t); mask in C-operand
        __builtin_amdgcn_s_setprio(1);
#pragma unroll
        for (int ks = 0; ks < 2; ++ks) {
            const s8v bq_ = ks ? qf1 : qf0;
#pragma unroll
            for (int js = 0; js < 4; ++js) {
                s8v ak0 = *(const s8v*)(K0 + (js * 16 + col16) * PT + ks * 32 + quad * 8);
                s8v ak1 = *(const s8v*)(K1 + (js * 16 + col16) * PT + ks * 32 + quad * 8);
                s0acc[js] = __builtin_amdgcn_mfma_f32_16x16x32_bf16(ak0, bq_, s0acc[js], 0, 0, 0);
                s1acc[js] = __builtin_amdgcn_mfma_f32_16x16x32_bf16(ak1, bq_, s1acc[js], 0, 0, 0);
            }
        }
        __builtin_amdgcn_s_setprio(0);

        // per-lane max over this lane's 32 S values
        float tm0 = fmaxf(fmaxf(s0acc[0][0], s0acc[0][1]), fmaxf(s0acc[0][2], s0acc[0][3]));
        float tm1 = fmaxf(fmaxf(s0acc[1][0], s0acc[1][1]), fmaxf(s0acc[1][2], s0acc[1][3]));
        float tm2 = fmaxf(fmaxf(s0acc[2][0], s0acc[2][1]), fmaxf(s0acc[2][2], s0acc[2][3]));
        float tm3 = fmaxf(fmaxf(s0acc[3][0], s0acc[3][1]), fmaxf(s0acc[3][2], s0acc[3][3]));
        float tn0 = fmaxf(fmaxf(s1acc[0][0], s1acc[0][1]), fmaxf(s1acc[0][2], s1acc[0][3]));
        float tn1 = fmaxf(fmaxf(s1acc[1][0], s1acc[1][1]), fmaxf(s1acc[1][2], s1acc[1][3]));
        float tn2 = fmaxf(fmaxf(s1acc[2][0], s1acc[2][1]), fmaxf(s1acc[2][2], s1acc[2][3]));
        float tn3 = fmaxf(fmaxf(s1acc[3][0], s1acc[3][1]), fmaxf(s1acc[3][2], s1acc[3][3]));
        float tmax = fmaxf(fmaxf(fmaxf(tm0, tm1), fmaxf(tm2, tm3)),
                           fmaxf(fmaxf(tn0, tn1), fmaxf(tn2, tn3)));

        // defer-max: rescale only if some lane's max grew past mrun + 10
        if (!__all(tmax - mrun <= 10.0f)) {
            float tfull = fmaxf(tmax, __shfl_xor(tmax, 16));
            tfull = fmaxf(tfull, __shfl_xor(tfull, 32));
            const float mnew = fmaxf(mrun, tfull);
            const float scl = __builtin_amdgcn_exp2f(mrun - mnew);  // 0 on 1st
            l4 *= scl;
            float sclr[4];
#pragma unroll
            for (int r = 0; r < 4; ++r) sclr[r] = __shfl(scl, quad * 4 + r);
#pragma unroll
            for (int jd = 0; jd < 4; ++jd)
#pragma unroll
                for (int r = 0; r < 4; ++r) oacc[jd][r] *= sclr[r];
            mrun = mnew;
        }

        // exp2 + pack to bf16 (pre-barrier-C; only stores go after C)
        unsigned pk0[8], pk1[8];
#pragma unroll
        for (int js = 0; js < 4; ++js) {
            f4v p0 = s0acc[js] - mrun;
            f4v p1 = s1acc[js] - mrun;
#pragma unroll
            for (int r = 0; r < 4; ++r) {
                p0[r] = __builtin_amdgcn_exp2f(p0[r]);
                p1[r] = __builtin_amdgcn_exp2f(p1[r]);
            }
            l4 += p0 + p1;
            __asm__("v_cvt_pk_bf16_f32 %0, %1, %2" : "=v"(pk0[js*2])   : "v"(p0[0]), "v"(p0[1]));
            __asm__("v_cvt_pk_bf16_f32 %0, %1, %2" : "=v"(pk0[js*2+1]) : "v"(p0[2]), "v"(p0[3]));
            __asm__("v_cvt_pk_bf16_f32 %0, %1, %2" : "=v"(pk1[js*2])   : "v"(p1[0]), "v"(p1[1]));
            __asm__("v_cvt_pk_bf16_f32 %0, %1, %2" : "=v"(pk1[js*2+1]) : "v"(p1[2]), "v"(p1[3]));
        }

        // T14b: V(next) in flight across P-store + PV (s-acc now dead)
        PREF_V(t2n)

        __syncthreads();  // (C) all waves done reading K0/K1

        // P store (wave-private rows) -> no barrier before readback
#pragma unroll
        for (int js = 0; js < 4; ++js) {
            *(uint2*)(K0 + myrow + js * 16 + quad * 4) = make_uint2(pk0[js*2], pk0[js*2+1]);
            *(uint2*)(K1 + myrow + js * 16 + quad * 4) = make_uint2(pk1[js*2], pk1[js*2+1]);
        }

        // O += P0.V0 + P1.V1 : A[m=t][k=tok] from K0/K1, B[n=d][k=tok]
        __builtin_amdgcn_s_setprio(1);
#pragma unroll
        for (int ks = 0; ks < 2; ++ks) {
            s8v p0 = *(const s8v*)(K0 + myrow + ks * 32 + quad * 8);
            s8v p1 = *(const s8v*)(K1 + myrow + ks * 32 + quad * 8);
#pragma unroll
            for (int jd = 0; jd < 4; ++jd) {
                s8v v0_ = *(const s8v*)(V0 + (jd * 16 + col16) * PT + ks * 32 + quad * 8);
                s8v v1_ = *(const s8v*)(V1 + (jd * 16 + col16) * PT + ks * 32 + quad * 8);
                oacc[jd] = __builtin_amdgcn_mfma_f32_16x16x32_bf16(p0, v0_, oacc[jd], 0, 0, 0);
                oacc[jd] = __builtin_amdgcn_mfma_f32_16x16x32_bf16(p1, v1_, oacc[jd], 0, 0, 0);
            }
        }
        __builtin_amdgcn_s_setprio(0);
    }
#undef PREF_K
#undef PREF_V
#undef PREF_M

    // epilogue: reduce row-sum partials, normalize and write bf16
    float lr = l4[0] + l4[1] + l4[2] + l4[3];
    lr += __shfl_xor(lr, 16);
    lr += __shfl_xor(lr, 32);
    const float inv = 1.0f / lr;
    float invr[4];
#pragma unroll
    for (int r = 0; r < 4; ++r) invr[r] = __shfl(inv, quad * 4 + r);
#pragma unroll
    for (int r = 0; r < 4; ++r) {
        const int t = t0 + w * 16 + quad * 4 + r;
#pragma unroll
        for (int jd = 0; jd < 4; ++jd)
            O[(size_t)(b_ * TT + t) * EE + h * HDIM + jd * 16 + col16] =
                f2bf(oacc[jd][r] * invr[r]);
    }
}

// ---------------------------------------------------------------------------
extern "C" void kernel_launch(void* const* d_in, const int* in_sizes, int n_in,
                              void* d_out, int out_size, void* d_ws, size_t ws_size,
                              hipStream_t stream)
{
    (void)in_sizes; (void)n_in; (void)out_size; (void)ws_size;

    const float* x    = (const float*)d_in[0];
    const float* mask = (const float*)d_in[1];
    const float* Wq   = (const float*)d_in[2];
    const float* bq   = (const float*)d_in[3];
    const float* Wk   = (const float*)d_in[4];
    const float* bk   = (const float*)d_in[5];
    const float* Wv   = (const float*)d_in[6];
    const float* bv   = (const float*)d_in[7];
    const float* Wo   = (const float*)d_in[8];
    const float* bo   = (const float*)d_in[9];
    float* out = (float*)d_out;

    // workspace carve (ushort units): 42M ushorts = 84 MB
    unsigned short* xb  = (unsigned short*)d_ws;
    unsigned short* wqb = xb  + (size_t)MROWS * EE;          // 4M
    unsigned short* wkb = wqb + (size_t)EE * EE;             // 1M
    unsigned short* wvb = wkb + (size_t)2 * EE * EE;         // 2M
    unsigned short* wob = wvb + (size_t)2 * EE * EE;         // 2M
    unsigned short* mb  = wob + (size_t)EE * EE;             // 1M
    unsigned short* qp  = mb  + (size_t)BB * TT * TT;        // 4M
    unsigned short* kp  = qp  + (size_t)MROWS * EE;          // 4M (plain [tok][2048])
    unsigned short* vt  = kp  + (size_t)BB * HH * SS * HDIM; // 8M (plain V^T [f][4096])
    unsigned short* ao  = vt  + (size_t)BB * HH * SS * HDIM; // 8M

    dim3 blk(256);

    // fused fp32->bf16 conversion (x + 4 weights + mask; mask *= log2e)
    cvt6_kernel<<<4096, blk, 0, stream>>>(x, Wq, Wk, Wv, Wo, mask,
                                          xb, wqb, wkb, wvb, wob, mb);
    // FUSED Q+K+V projection: grid (32,40) = 1280 blocks, plain epilogues
    gemm_qkv_kernel<<<dim3(32, 40), blk, 0, stream>>>(
        xb, wqb, wkb, wvb, bq, bk, bv, qp, kp, vt);
    // attention ((mm,t)-ordered halves over plain K/V layouts)
    attn_mfma12_kernel<<<dim3(1024), blk, 0, stream>>>(qp, kp, vt, mb, ao);
    // output projection -> fp32 out (128x64 tile: 512 blocks, 2/CU)
    gemm_out_kernel<EE, EE, 128, 64><<<dim3(32, 16), blk, 0, stream>>>(
        ao, wob, bo, out);
}

// Round 14
// 265.173 us; speedup vs baseline: 1.0083x; 1.0060x over previous
//
#include <hip/hip_runtime.h>
#include <math.h>

// Problem constants (fixed by the reference)
#define BB    4
#define TT    1024
#define EE    1024
#define HH    16
#define HDIM  64
#define SS    2048            // T * MULT
#define MROWS 4096            // B * T
// Q scale with log2(e) folded in: softmax runs in exp2 domain.
#define QSCALE 0.18033688011112f   // 0.125 * log2(e)
#define LOG2E  1.4426950408889634f

typedef short  s8v  __attribute__((ext_vector_type(8)));   // 8 bf16 (4 VGPRs)
typedef float  f4v  __attribute__((ext_vector_type(4)));   // 4 fp32 acc

__device__ __forceinline__ unsigned short f2bf(float f) {
    union { float f; unsigned u; } c; c.f = f;
    unsigned u = c.u + 0x7FFFu + ((c.u >> 16) & 1u);   // RNE
    return (unsigned short)(u >> 16);
}
__device__ __forceinline__ float bflo(unsigned u) {
    union { unsigned u; float f; } c; c.u = u << 16; return c.f;
}
__device__ __forceinline__ float bfhi(unsigned u) {
    union { unsigned u; float f; } c; c.u = u & 0xffff0000u; return c.f;
}

// async global->LDS, 16B per lane. LDS dest = wave-uniform base + lane*16.
__device__ __forceinline__ void async16(const void* g, void* l) {
    __builtin_amdgcn_global_load_lds(
        (const __attribute__((address_space(1))) unsigned int*)g,
        (__attribute__((address_space(3))) unsigned int*)l,
        16, 0, 0);
}

// ---------------------------------------------------------------------------
// Fused fp32->bf16 convert: x, Wq, Wk, Wv, Wo, mask in one launch.
// Mask is additionally scaled by log2(e) (softmax runs in exp2 domain).
// ---------------------------------------------------------------------------
__global__ __launch_bounds__(256) void cvt6_kernel(
    const float* __restrict__ x,  const float* __restrict__ wq,
    const float* __restrict__ wk, const float* __restrict__ wv,
    const float* __restrict__ wo, const float* __restrict__ mk,
    unsigned short* __restrict__ xb,  unsigned short* __restrict__ wqb,
    unsigned short* __restrict__ wkb, unsigned short* __restrict__ wvb,
    unsigned short* __restrict__ wob, unsigned short* __restrict__ mbb)
{
    const int total = 3670016;
    int i = blockIdx.x * 256 + threadIdx.x;
    const int stride = gridDim.x * 256;
    for (; i < total; i += stride) {
        const float* s; unsigned short* d; int off; float sc = 1.0f;
        if (i < 1048576)      { s = x;  d = xb;  off = i; }
        else if (i < 1310720) { s = wq; d = wqb; off = i - 1048576; }
        else if (i < 1835008) { s = wk; d = wkb; off = i - 1310720; }
        else if (i < 2359296) { s = wv; d = wvb; off = i - 1835008; }
        else if (i < 2621440) { s = wo; d = wob; off = i - 2359296; }
        else                  { s = mk; d = mbb; off = i - 2621440; sc = LOG2E; }
        float4 v = ((const float4*)s)[off];
        ushort4 o;
        o.x = f2bf(v.x * sc); o.y = f2bf(v.y * sc);
        o.z = f2bf(v.z * sc); o.w = f2bf(v.w * sc);
        ((ushort4*)d)[off] = o;
    }
}

// ---------------------------------------------------------------------------
// FUSED Q+K+V projection (one launch, grid (32,40)):
//   y in [0,8)   : Q = x @ Wq^T  -> qp plain bf16 [token][1024], QSCALE'd
//   y in [8,24)  : K = x @ Wk^T  -> kp plain bf16 [token][2048]
//   y in [24,40) : V = Wv @ x^T  -> vt plain bf16 V^T [feature 2048][4096]
// v12's scalar 2B stores caused ~2x write RMW (WRITE 81 MB vs 40 ideal).
// v13: SWAPPED-OPERAND MFMA (D^T fragments: lane holds 4 consecutive n of
// one row m) -> cvt_pk to uint2 -> LDS transpose (pitch 136) -> all threads
// store uint4 (16 B/lane, full 64 B lines, zero RMW). 2 half-tile passes.
// ---------------------------------------------------------------------------
__global__ __launch_bounds__(256, 4) void gemm_qkv_kernel(
    const unsigned short* __restrict__ X,  const unsigned short* __restrict__ Wq,
    const unsigned short* __restrict__ Wk, const unsigned short* __restrict__ Wv,
    const float* __restrict__ bq, const float* __restrict__ bk,
    const float* __restrict__ bv, unsigned short* __restrict__ qp,
    unsigned short* __restrict__ kp, unsigned short* __restrict__ vt)
{
    constexpr int EPT = 136;   // epilogue LDS pitch (ushorts): ~2-way banks
    __shared__ __align__(16) unsigned short S[64 * EPT];   // 17408 B
    unsigned short* As = S;                 // K-loop staging aliases (8 KB)
    unsigned short* Bs = S + 128 * 32;      // (8 KB)

    const int tid = threadIdx.x;
    const int lane = tid & 63, w = tid >> 6;
    const int wm = (w & 1) * 64, wn = (w >> 1) * 64;
    const int col16 = lane & 15, quad = lane >> 4;
    const int y = blockIdx.y;
    const int part = (y < 8) ? 0 : (y < 24) ? 1 : 2;   // 0=Q 1=K 2=V

    // panel row bases: am0 = A rows, wn0 = W rows (both 128-row panels, K=1024)
    int am0, wn0;
    const unsigned short *Apan, *Wpan;
    if (part == 0) {        // Q: A = x tokens, W = Wq rows
        am0 = blockIdx.x * 128; wn0 = y * 128;
        Apan = X + (size_t)am0 * EE;  Wpan = Wq + (size_t)wn0 * EE;
    } else if (part == 1) { // K: A = x tokens, W = Wk rows
        am0 = blockIdx.x * 128; wn0 = (y - 8) * 128;
        Apan = X + (size_t)am0 * EE;  Wpan = Wk + (size_t)wn0 * EE;
    } else {                // V: A = Wv feature rows, W = x tokens
        am0 = (y - 24) * 128; wn0 = blockIdx.x * 128;
        Apan = Wv + (size_t)am0 * EE; Wpan = X + (size_t)wn0 * EE;
    }

    f4v acc[4][4];
#pragma unroll
    for (int i = 0; i < 4; ++i)
#pragma unroll
        for (int j = 0; j < 4; ++j) acc[i][j] = (f4v)0.0f;

    for (int k0 = 0; k0 < EE; k0 += 32) {
#pragma unroll
        for (int it = 0; it < 2; ++it) {
            int f = (it * 4 + w) * 64 + lane;
            int r = f >> 2, g = (f & 3) * 8;
            async16(Apan + (size_t)r * EE + k0 + g, As + (it * 4 + w) * 512);
            async16(Wpan + (size_t)r * EE + k0 + g, Bs + (it * 4 + w) * 512);
        }
        __syncthreads();
        s8v af[4], bf[4];
#pragma unroll
        for (int i = 0; i < 4; ++i)
            af[i] = *(const s8v*)(As + (wm + i * 16 + col16) * 32 + quad * 8);
#pragma unroll
        for (int j = 0; j < 4; ++j)
            bf[j] = *(const s8v*)(Bs + (wn + j * 16 + col16) * 32 + quad * 8);
        // SWAPPED operands: D^T fragment -- lane holds m = (i-tile)+col16,
        // n = (j-tile)+quad*4+r (4 consecutive cols of one row)
#pragma unroll
        for (int i = 0; i < 4; ++i)
#pragma unroll
            for (int j = 0; j < 4; ++j)
                acc[i][j] = __builtin_amdgcn_mfma_f32_16x16x32_bf16(
                    bf[j], af[i], acc[i][j], 0, 0, 0);
        __syncthreads();
    }

    // Epilogue: 2 half-tile passes through LDS -> coalesced 16 B/lane stores.
    // Pass p handles rows [p*64, p*64+64): owned by waves with wm == p*64.
#pragma unroll
    for (int p = 0; p < 2; ++p) {
        __syncthreads();   // LDS free (K-loop reads / prev pass reads done)
        if ((w & 1) == p) {
#pragma unroll
            for (int i = 0; i < 4; ++i) {
                const float bm = (part == 2) ? bv[am0 + wm + i * 16 + col16] : 0.0f;
#pragma unroll
                for (int j = 0; j < 4; ++j) {
                    float c0, c1, c2, c3;
                    if (part == 2) {
                        c0 = acc[i][j][0] + bm; c1 = acc[i][j][1] + bm;
                        c2 = acc[i][j][2] + bm; c3 = acc[i][j][3] + bm;
                    } else {
                        const float* bb = (part == 0) ? bq : bk;
                        float4 b4 = *(const float4*)(bb + wn0 + wn + j * 16 + quad * 4);
                        c0 = acc[i][j][0] + b4.x; c1 = acc[i][j][1] + b4.y;
                        c2 = acc[i][j][2] + b4.z; c3 = acc[i][j][3] + b4.w;
                        if (part == 0) {
                            c0 *= QSCALE; c1 *= QSCALE; c2 *= QSCALE; c3 *= QSCALE;
                        }
                    }
                    unsigned lo, hi;
                    __asm__("v_cvt_pk_bf16_f32 %0, %1, %2" : "=v"(lo) : "v"(c0), "v"(c1));
                    __asm__("v_cvt_pk_bf16_f32 %0, %1, %2" : "=v"(hi) : "v"(c2), "v"(c3));
                    *(uint2*)(S + (i * 16 + col16) * EPT + wn + j * 16 + quad * 4) =
                        make_uint2(lo, hi);
                }
            }
        }
        __syncthreads();
        // all 256 threads: row-major readback + full-line global stores
#pragma unroll
        for (int s = 0; s < 4; ++s) {
            const int rr = (tid >> 4) + s * 16;        // 0..63
            const int cc = (tid & 15) * 8;             // 0..120
            uint4 vv = *(const uint4*)(S + rr * EPT + cc);
            const int gm = am0 + p * 64 + rr;
            if (part == 0)
                *(uint4*)(qp + (size_t)gm * 1024 + wn0 + cc) = vv;
            else if (part == 1)
                *(uint4*)(kp + (size_t)gm * 2048 + wn0 + cc) = vv;
            else
                *(uint4*)(vt + (size_t)gm * 4096 + wn0 + cc) = vv;
        }
    }
}

// ---------------------------------------------------------------------------
// Output-projection GEMM C = A @ W^T + bias -> fp32, rectangular BM x BN.
// (fp32 scalar stores are already full-line coalesced: 16 lanes x 4 B.)
// ---------------------------------------------------------------------------
template <int Ksz, int Nsz, int BM, int BN>
__global__ __launch_bounds__(256, 4) void gemm_out_kernel(
    const unsigned short* __restrict__ A, const unsigned short* __restrict__ W,
    const float* __restrict__ bias, float* __restrict__ Cout)
{
    constexpr int WM = BM / 2, WN = BN / 2;
    constexpr int MI = WM / 16, NJ = WN / 16;
    __shared__ __align__(16) unsigned short As[BM * 32];
    __shared__ __align__(16) unsigned short Bs[BN * 32];

    const int tid = threadIdx.x;
    const int lane = tid & 63, w = tid >> 6;
    const int wm = (w & 1) * WM, wn = (w >> 1) * WN;
    const int col16 = lane & 15, quad = lane >> 4;
    const int m0 = blockIdx.x * BM;
    const int n0 = blockIdx.y * BN;

    f4v acc[MI][NJ];
#pragma unroll
    for (int i = 0; i < MI; ++i)
#pragma unroll
        for (int j = 0; j < NJ; ++j) acc[i][j] = (f4v)0.0f;

    for (int k0 = 0; k0 < Ksz; k0 += 32) {
#pragma unroll
        for (int it = 0; it < BM / 64; ++it) {
            int f = (it * 4 + w) * 64 + lane;
            int r = f >> 2, g = (f & 3) * 8;
            async16(A + (size_t)(m0 + r) * Ksz + k0 + g, As + (it * 4 + w) * 512);
        }
#pragma unroll
        for (int it = 0; it < BN / 64; ++it) {
            int f = (it * 4 + w) * 64 + lane;
            int r = f >> 2, g = (f & 3) * 8;
            async16(W + (size_t)(n0 + r) * Ksz + k0 + g, Bs + (it * 4 + w) * 512);
        }
        __syncthreads();
        s8v af[MI], bf[NJ];
#pragma unroll
        for (int i = 0; i < MI; ++i)
            af[i] = *(const s8v*)(As + (wm + i * 16 + col16) * 32 + quad * 8);
#pragma unroll
        for (int j = 0; j < NJ; ++j)
            bf[j] = *(const s8v*)(Bs + (wn + j * 16 + col16) * 32 + quad * 8);
#pragma unroll
        for (int i = 0; i < MI; ++i)
#pragma unroll
            for (int j = 0; j < NJ; ++j)
                acc[i][j] = __builtin_amdgcn_mfma_f32_16x16x32_bf16(
                    af[i], bf[j], acc[i][j], 0, 0, 0);
        __syncthreads();
    }

#pragma unroll
    for (int j = 0; j < NJ; ++j) {
        const int n = n0 + wn + j * 16 + col16;
        const float bn = bias[n];
#pragma unroll
        for (int i = 0; i < MI; ++i) {
            const int mb = m0 + wm + i * 16 + quad * 4;
#pragma unroll
            for (int r = 0; r < 4; ++r) {
                const int m = mb + r;
                Cout[(size_t)m * Nsz + n] = acc[i][j][r] + bn;
            }
        }
    }
}

// ---------------------------------------------------------------------------
// Flash attention v12 (FROZEN): v5 pipeline with (mm,t)-ordered halves over
// plain K/V layouts. Verified passing (r13). See r12 commentary.
// ---------------------------------------------------------------------------
__global__ __launch_bounds__(256, 4) void attn_mfma12_kernel(
    const unsigned short* __restrict__ Q, const unsigned short* __restrict__ Kp,
    const unsigned short* __restrict__ Vt, const unsigned short* __restrict__ Mb,
    unsigned short* __restrict__ O)
{
    constexpr int PT = 68;   // 136B pitch: conflict-free b128/b64 patterns
    __shared__ __align__(16) unsigned short K0[64 * PT];  // K mm=0, then P0
    __shared__ __align__(16) unsigned short K1[64 * PT];  // K mm=1, then P1
    __shared__ __align__(16) unsigned short V0[64 * PT];  // V^T mm=0 [d][t]
    __shared__ __align__(16) unsigned short V1[64 * PT];  // V^T mm=1 [d][t]

    const int tid = threadIdx.x;
    const int lane = tid & 63, w = tid >> 6;
    const int col16 = lane & 15, quad = lane >> 4;

    // XCD swizzle: v = gid&7 (virtual XCD), bh = v*8 + (j>>4), t0 = (j&15)*64
    const int gid = blockIdx.x;
    const int v = gid & 7, j = gid >> 3;
    const int bh = v * 8 + (j >> 4);
    const int t0 = (j & 15) * 64;
    const int b_ = bh >> 4, h = bh & 15;

    // Q fragments in registers: this lane's t-row = w*16+col16, k-slices
    const unsigned short* Qrow =
        Q + (size_t)(b_ * TT + t0 + w * 16 + col16) * EE + h * HDIM;
    const s8v qf0 = *(const s8v*)(Qrow + quad * 8);
    const s8v qf1 = *(const s8v*)(Qrow + 32 + quad * 8);

    f4v oacc[4];
#pragma unroll
    for (int jd = 0; jd < 4; ++jd) oacc[jd] = (f4v)0.0f;
    float mrun = -INFINITY;
    f4v l4 = (f4v)0.0f;           // per-lane partial row-sum (4 s-slots)

    // plain-layout bases (mm halves)
    const unsigned short* Kb0 = Kp + (size_t)(b_ * 1024) * 2048 + h * 64;
    const unsigned short* Kb1 = Kb0 + 1024;                       // mm=1
    const unsigned short* Vb0 = Vt + (size_t)(h * 64) * 4096 + b_ * 1024;
    const unsigned short* Vb1 = Vb0 + (size_t)1024 * 4096;        // mm=1
    const unsigned short* Mrow = Mb + (size_t)b_ * TT * TT
                               + (size_t)(t0 + w * 16 + col16) * TT;
    const int myrow = (w * 16 + col16) * PT;   // this lane's t-row in LDS
    const int r0 = tid >> 3, c0 = (tid & 7) * 8;   // staging row/col

    // T14 staged tile: NAMED registers only (arrays risk scratch demotion)
    uint4 kA0, kA1, kB0, kB1;   // K mm0/mm1, rows r0 and r0+32
    uint4 vA0, vA1, vB0, vB1;   // V^T mm0/mm1
    uint4 mA0, mA1, mA2, mA3;   // mask cols (2tk)&1023..+7 per js

#define PREF_K(T2B)                                                            \
    kA0 = *(const uint4*)(Kb0 + (size_t)((T2B) + r0) * 2048 + c0);             \
    kA1 = *(const uint4*)(Kb0 + (size_t)((T2B) + r0 + 32) * 2048 + c0);        \
    kB0 = *(const uint4*)(Kb1 + (size_t)((T2B) + r0) * 2048 + c0);             \
    kB1 = *(const uint4*)(Kb1 + (size_t)((T2B) + r0 + 32) * 2048 + c0);
#define PREF_V(T2B)                                                            \
    vA0 = *(const uint4*)(Vb0 + (size_t)r0 * 4096 + (T2B) + c0);               \
    vA1 = *(const uint4*)(Vb0 + (size_t)(r0 + 32) * 4096 + (T2B) + c0);        \
    vB0 = *(const uint4*)(Vb1 + (size_t)r0 * 4096 + (T2B) + c0);               \
    vB1 = *(const uint4*)(Vb1 + (size_t)(r0 + 32) * 4096 + (T2B) + c0);
#define PREF_M(T2B)                                                            \
    {                                                                          \
        const unsigned short* Mx = Mrow + ((2 * (T2B)) & 1023);                \
        mA0 = *(const uint4*)(Mx + 0 * 32 + quad * 8);                         \
        mA1 = *(const uint4*)(Mx + 1 * 32 + quad * 8);                         \
        mA2 = *(const uint4*)(Mx + 2 * 32 + quad * 8);                         \
        mA3 = *(const uint4*)(Mx + 3 * 32 + quad * 8);                         \
    }

    // prologue: tile 0 fully staged
    PREF_K(0)
    PREF_V(0)
    PREF_M(0)

    for (int it16 = 0; it16 < 16; ++it16) {
        __syncthreads();  // (A) prev iteration's PV reads done

        // write staged tile (regs -> LDS); loads long since completed
        *(uint4*)(K0 + r0 * PT + c0)        = kA0;
        *(uint4*)(K0 + (r0 + 32) * PT + c0) = kA1;
        *(uint4*)(K1 + r0 * PT + c0)        = kB0;
        *(uint4*)(K1 + (r0 + 32) * PT + c0) = kB1;
        *(uint4*)(V0 + r0 * PT + c0)        = vA0;
        *(uint4*)(V0 + (r0 + 32) * PT + c0) = vA1;
        *(uint4*)(V1 + r0 * PT + c0)        = vB0;
        *(uint4*)(V1 + (r0 + 32) * PT + c0) = vB1;

        // S-acc init from mask regs: even ushorts -> mm0, odd -> mm1
        f4v s0acc[4], s1acc[4];
        {
            f4v mv;
            mv[0] = bflo(mA0.x); mv[1] = bflo(mA0.y);
            mv[2] = bflo(mA0.z); mv[3] = bflo(mA0.w); s0acc[0] = mv;
            mv[0] = bfhi(mA0.x); mv[1] = bfhi(mA0.y);
            mv[2] = bfhi(mA0.z); mv[3] = bfhi(mA0.w); s1acc[0] = mv;
            mv[0] = bflo(mA1.x); mv[1] = bflo(mA1.y);
            mv[2] = bflo(mA1.z); mv[3] = bflo(mA1.w); s0acc[1] = mv;
            mv[0] = bfhi(mA1.x); mv[1] = bfhi(mA1.y);
            mv[2] = bfhi(mA1.z); mv[3] = bfhi(mA1.w); s1acc[1] = mv;
            mv[0] = bflo(mA2.x); mv[1] = bflo(mA2.y);
            mv[2] = bflo(mA2.z); mv[3] = bflo(mA2.w); s0acc[2] = mv;
            mv[0] = bfhi(mA2.x); mv[1] = bfhi(mA2.y);
            mv[2] = bfhi(mA2.z); mv[3] = bfhi(mA2.w); s1acc[2] = mv;
            mv[0] = bflo(mA3.x); mv[1] = bflo(mA3.y);
            mv[2] = bflo(mA3.z); mv[3] = bflo(mA3.w); s0acc[3] = mv;
            mv[0] = bfhi(mA3.x); mv[1] = bfhi(mA3.y);
            mv[2] = bfhi(mA3.z); mv[3] = bfhi(mA3.w); s1acc[3] = mv;
        }

        // T14a: K(next)+mask(next) in flight across the whole compute phase
        const int t2n = ((it16 + 1) & 15) * 64;
        PREF_K(t2n)
        PREF_M(t2n)

        __syncthreads();  // (B) staged tile visible to all waves

        // S^T halves: A=K (m=token-row), B=Q (n=t); mask in C-operand
        __builtin_amdgcn_s_setprio(1);
#pragma unroll
        for (int ks = 0; ks < 2; ++ks) {
            const s8v bq_ = ks ? qf1 : qf0;
#pragma unroll
            for (int js = 0; js < 4; ++js) {
                s8v ak0 = *(const s8v*)(K0 + (js * 16 + col16) * PT + ks * 32 + quad * 8);
                s8v ak1 = *(const s8v*)(K1 + (js * 16 + col16) * PT + ks * 32 + quad * 8);
                s0acc[js] = __builtin_amdgcn_mfma_f32_16x16x32_bf16(ak0, bq_, s0acc[js], 0, 0, 0);
                s1acc[js] = __builtin_amdgcn_mfma_f32_16x16x32_bf16(ak1, bq_, s1acc[js], 0, 0, 0);
            }
        }
        __builtin_amdgcn_s_setprio(0);

        // per-lane max over this lane's 32 S values
        float tm0 = fmaxf(fmaxf(s0acc[0][0], s0acc[0][1]), fmaxf(s0acc[0][2], s0acc[0][3]));
        float tm1 = fmaxf(fmaxf(s0acc[1][0], s0acc[1][1]), fmaxf(s0acc[1][2], s0acc[1][3]));
        float tm2 = fmaxf(fmaxf(s0acc[2][0], s0acc[2][1]), fmaxf(s0acc[2][2], s0acc[2][3]));
        float tm3 = fmaxf(fmaxf(s0acc[3][0], s0acc[3][1]), fmaxf(s0acc[3][2], s0acc[3][3]));
        float tn0 = fmaxf(fmaxf(s1acc[0][0], s1acc[0][1]), fmaxf(s1acc[0][2], s1acc[0][3]));
        float tn1 = fmaxf(fmaxf(s1acc[1][0], s1acc[1][1]), fmaxf(s1acc[1][2], s1acc[1][3]));
        float tn2 = fmaxf(fmaxf(s1acc[2][0], s1acc[2][1]), fmaxf(s1acc[2][2], s1acc[2][3]));
        float tn3 = fmaxf(fmaxf(s1acc[3][0], s1acc[3][1]), fmaxf(s1acc[3][2], s1acc[3][3]));
        float tmax = fmaxf(fmaxf(fmaxf(tm0, tm1), fmaxf(tm2, tm3)),
                           fmaxf(fmaxf(tn0, tn1), fmaxf(tn2, tn3)));

        // defer-max: rescale only if some lane's max grew past mrun + 10
        if (!__all(tmax - mrun <= 10.0f)) {
            float tfull = fmaxf(tmax, __shfl_xor(tmax, 16));
            tfull = fmaxf(tfull, __shfl_xor(tfull, 32));
            const float mnew = fmaxf(mrun, tfull);
            const float scl = __builtin_amdgcn_exp2f(mrun - mnew);  // 0 on 1st
            l4 *= scl;
            float sclr[4];
#pragma unroll
            for (int r = 0; r < 4; ++r) sclr[r] = __shfl(scl, quad * 4 + r);
#pragma unroll
            for (int jd = 0; jd < 4; ++jd)
#pragma unroll
                for (int r = 0; r < 4; ++r) oacc[jd][r] *= sclr[r];
            mrun = mnew;
        }

        // exp2 + pack to bf16 (pre-barrier-C; only stores go after C)
        unsigned pk0[8], pk1[8];
#pragma unroll
        for (int js = 0; js < 4; ++js) {
            f4v p0 = s0acc[js] - mrun;
            f4v p1 = s1acc[js] - mrun;
#pragma unroll
            for (int r = 0; r < 4; ++r) {
                p0[r] = __builtin_amdgcn_exp2f(p0[r]);
                p1[r] = __builtin_amdgcn_exp2f(p1[r]);
            }
            l4 += p0 + p1;
            __asm__("v_cvt_pk_bf16_f32 %0, %1, %2" : "=v"(pk0[js*2])   : "v"(p0[0]), "v"(p0[1]));
            __asm__("v_cvt_pk_bf16_f32 %0, %1, %2" : "=v"(pk0[js*2+1]) : "v"(p0[2]), "v"(p0[3]));
            __asm__("v_cvt_pk_bf16_f32 %0, %1, %2" : "=v"(pk1[js*2])   : "v"(p1[0]), "v"(p1[1]));
            __asm__("v_cvt_pk_bf16_f32 %0, %1, %2" : "=v"(pk1[js*2+1]) : "v"(p1[2]), "v"(p1[3]));
        }

        // T14b: V(next) in flight across P-store + PV (s-acc now dead)
        PREF_V(t2n)

        __syncthreads();  // (C) all waves done reading K0/K1

        // P store (wave-private rows) -> no barrier before readback
#pragma unroll
        for (int js = 0; js < 4; ++js) {
            *(uint2*)(K0 + myrow + js * 16 + quad * 4) = make_uint2(pk0[js*2], pk0[js*2+1]);
            *(uint2*)(K1 + myrow + js * 16 + quad * 4) = make_uint2(pk1[js*2], pk1[js*2+1]);
        }

        // O += P0.V0 + P1.V1 : A[m=t][k=tok] from K0/K1, B[n=d][k=tok]
        __builtin_amdgcn_s_setprio(1);
#pragma unroll
        for (int ks = 0; ks < 2; ++ks) {
            s8v p0 = *(const s8v*)(K0 + myrow + ks * 32 + quad * 8);
            s8v p1 = *(const s8v*)(K1 + myrow + ks * 32 + quad * 8);
#pragma unroll
            for (int jd = 0; jd < 4; ++jd) {
                s8v v0_ = *(const s8v*)(V0 + (jd * 16 + col16) * PT + ks * 32 + quad * 8);
                s8v v1_ = *(const s8v*)(V1 + (jd * 16 + col16) * PT + ks * 32 + quad * 8);
                oacc[jd] = __builtin_amdgcn_mfma_f32_16x16x32_bf16(p0, v0_, oacc[jd], 0, 0, 0);
                oacc[jd] = __builtin_amdgcn_mfma_f32_16x16x32_bf16(p1, v1_, oacc[jd], 0, 0, 0);
            }
        }
        __builtin_amdgcn_s_setprio(0);
    }
#undef PREF_K
#undef PREF_V
#undef PREF_M

    // epilogue: reduce row-sum partials, normalize and write bf16
    float lr = l4[0] + l4[1] + l4[2] + l4[3];
    lr += __shfl_xor(lr, 16);
    lr += __shfl_xor(lr, 32);
    const float inv = 1.0f / lr;
    float invr[4];
#pragma unroll
    for (int r = 0; r < 4; ++r) invr[r] = __shfl(inv, quad * 4 + r);
#pragma unroll
    for (int r = 0; r < 4; ++r) {
        const int t = t0 + w * 16 + quad * 4 + r;
#pragma unroll
        for (int jd = 0; jd < 4; ++jd)
            O[(size_t)(b_ * TT + t) * EE + h * HDIM + jd * 16 + col16] =
                f2bf(oacc[jd][r] * invr[r]);
    }
}

// ---------------------------------------------------------------------------
extern "C" void kernel_launch(void* const* d_in, const int* in_sizes, int n_in,
                              void* d_out, int out_size, void* d_ws, size_t ws_size,
                              hipStream_t stream)
{
    (void)in_sizes; (void)n_in; (void)out_size; (void)ws_size;

    const float* x    = (const float*)d_in[0];
    const float* mask = (const float*)d_in[1];
    const float* Wq   = (const float*)d_in[2];
    const float* bq   = (const float*)d_in[3];
    const float* Wk   = (const float*)d_in[4];
    const float* bk   = (const float*)d_in[5];
    const float* Wv   = (const float*)d_in[6];
    const float* bv   = (const float*)d_in[7];
    const float* Wo   = (const float*)d_in[8];
    const float* bo   = (const float*)d_in[9];
    float* out = (float*)d_out;

    // workspace carve (ushort units): 42M ushorts = 84 MB
    unsigned short* xb  = (unsigned short*)d_ws;
    unsigned short* wqb = xb  + (size_t)MROWS * EE;          // 4M
    unsigned short* wkb = wqb + (size_t)EE * EE;             // 1M
    unsigned short* wvb = wkb + (size_t)2 * EE * EE;         // 2M
    unsigned short* wob = wvb + (size_t)2 * EE * EE;         // 2M
    unsigned short* mb  = wob + (size_t)EE * EE;             // 1M
    unsigned short* qp  = mb  + (size_t)BB * TT * TT;        // 4M
    unsigned short* kp  = qp  + (size_t)MROWS * EE;          // 4M (plain [tok][2048])
    unsigned short* vt  = kp  + (size_t)BB * HH * SS * HDIM; // 8M (plain V^T [f][4096])
    unsigned short* ao  = vt  + (size_t)BB * HH * SS * HDIM; // 8M

    dim3 blk(256);

    // fused fp32->bf16 conversion (x + 4 weights + mask; mask *= log2e)
    cvt6_kernel<<<4096, blk, 0, stream>>>(x, Wq, Wk, Wv, Wo, mask,
                                          xb, wqb, wkb, wvb, wob, mb);
    // FUSED Q+K+V projection: swapped-operand MFMA + LDS-transposed
    // coalesced epilogue (16 B/lane stores, zero write-RMW)
    gemm_qkv_kernel<<<dim3(32, 40), blk, 0, stream>>>(
        xb, wqb, wkb, wvb, bq, bk, bv, qp, kp, vt);
    // attention ((mm,t)-ordered halves over plain K/V layouts, frozen)
    attn_mfma12_kernel<<<dim3(1024), blk, 0, stream>>>(qp, kp, vt, mb, ao);
    // output projection -> fp32 out (128x64 tile: 512 blocks, 2/CU)
    gemm_out_kernel<EE, EE, 128, 64><<<dim3(32, 16), blk, 0, stream>>>(
        ao, wob, bo, out);
}